// Round 18
// baseline (388.435 us; speedup 1.0000x reference)
//
#include <hip/hip_runtime.h>
#include <hip/hip_bf16.h>

#define NS    32768    // samples
#define NA    1024     // atoms
#define AL    2048     // atom length
#define KKEEP 1024     // top-k
#define CAPC  (512*1024)

struct Cand { float v; unsigned idx; };

typedef short  short8  __attribute__((ext_vector_type(8)));
typedef short  short4v __attribute__((ext_vector_type(4)));
typedef float  f32x4   __attribute__((ext_vector_type(4)));

// ---------------------------------------------------------------------------
// ws layout (bytes):
//   0       : float hdr[3]   { sumsq x[b=0], sumsq x[b=1], sumsq atoms }
//   16      : unsigned candCnt[2]   (zeroed by prep's last block)
//   32      : unsigned done[2]      (monotone counters; mod-gridsize logic ->
//                                    poison-proof, replay-deterministic)
//   64      : float psum[2048][3]   (24 KB, per-prep-block partials)
//   32768   : Cand sel[2][KKEEP]
//   65536   : unsigned short ab16[1024*2048]   (4 MB, bf16 atoms)
//   4259840 : Cand cand[2][cap]
//
// 4 nodes (prep, fm, refine+select, recon).
// r11/r17 lesson: fm must read only two scalars from hdr (any in-fm reduce
// costs 80-150 us).  r12/r13: fm must not touch af32.  This round: refine и
// select merged via the done-counter pattern (validated in prep r17) to drop
// one node (~20 us of launch/drain gap).
//
// Numerics contract (unchanged):
//   fm (bf16 MFMA) error: std ~4.2e-4 abs (~0.002 sigma_fm)
//   candidate filter T0 = 3.70*sig; true top-1024 cutoff ~ 4.01*sig
//   fp64 refine band TB = 3.85*sig: every candidate at/above the cutoff is
//   refined exactly; unrefined candidates can never be selected.
// ---------------------------------------------------------------------------

__device__ inline unsigned short f2bf(float f) {
    union { float f; unsigned u; } v; v.f = f;
    unsigned r = v.u + 0x7fffu + ((v.u >> 16) & 1u);   // round-to-nearest-even
    return (unsigned short)(r >> 16);
}

// ---------------------------------------------------------------------------
// prep: atoms f32->bf16 convert + per-block partials; the LAST block (done-
// counter, mod-2048) reduces psum -> hdr in fixed order + zeroes candCnt.
// ---------------------------------------------------------------------------
__global__ void prep_kernel(const float* __restrict__ x, const float* __restrict__ atoms,
                            float* __restrict__ psum, float* __restrict__ hdr,
                            unsigned* __restrict__ candCnt, unsigned* __restrict__ done,
                            unsigned short* __restrict__ ab16) {
    __shared__ float red[12];
    __shared__ int   isLast;
    const int bid = blockIdx.x;                       // grid = 2048
    const int tid = threadIdx.x;
    const int i   = bid * 256 + tid;
    float4 f = *(const float4*)(atoms + (size_t)i * 4);
    ushort4 o;
    o.x = f2bf(f.x); o.y = f2bf(f.y); o.z = f2bf(f.z); o.w = f2bf(f.w);
    *(ushort4*)(ab16 + (size_t)i * 4) = o;
    float sa  = f.x*f.x + f.y*f.y + f.z*f.z + f.w*f.w;
    float sx0 = 0.f, sx1 = 0.f;
    if (i < 16384) {
        float4 xv = *(const float4*)(x + (size_t)i * 4);
        float s = xv.x*xv.x + xv.y*xv.y + xv.z*xv.z + xv.w*xv.w;
        if (i < 8192) sx0 = s; else sx1 = s;
    }
    #pragma unroll
    for (int off = 32; off >= 1; off >>= 1) {
        sa  += __shfl_down(sa , off);
        sx0 += __shfl_down(sx0, off);
        sx1 += __shfl_down(sx1, off);
    }
    if ((tid & 63) == 0) {
        red[(tid >> 6) * 3 + 0] = sa;
        red[(tid >> 6) * 3 + 1] = sx0;
        red[(tid >> 6) * 3 + 2] = sx1;
    }
    __syncthreads();
    if (tid == 0) {
        psum[bid * 3 + 0] = red[0] + red[3] + red[6] + red[9];
        psum[bid * 3 + 1] = red[1] + red[4] + red[7] + red[10];
        psum[bid * 3 + 2] = red[2] + red[5] + red[8] + red[11];
        __threadfence();                              // release psum
        unsigned old = atomicAdd(done, 1u);
        isLast = (((old + 1u) & 2047u) == 0u) ? 1 : 0;
    }
    __syncthreads();
    if (!isLast) return;

    __threadfence();                                  // acquire psum
    float pa = 0.f, p0s = 0.f, p1s = 0.f;
    for (int j = tid; j < 2048; j += 256) {
        pa  += psum[3 * j + 0];
        p0s += psum[3 * j + 1];
        p1s += psum[3 * j + 2];
    }
    #pragma unroll
    for (int off = 32; off >= 1; off >>= 1) {
        pa  += __shfl_down(pa , off);
        p0s += __shfl_down(p0s, off);
        p1s += __shfl_down(p1s, off);
    }
    __syncthreads();                                  // red[] reuse guard
    if ((tid & 63) == 0) {
        red[(tid >> 6) * 3 + 0] = pa;
        red[(tid >> 6) * 3 + 1] = p0s;
        red[(tid >> 6) * 3 + 2] = p1s;
    }
    __syncthreads();
    if (tid == 0) {
        hdr[0] = red[1] + red[4] + red[7] + red[10];  // sumsq x[b=0]
        hdr[1] = red[2] + red[5] + red[8] + red[11];  // sumsq x[b=1]
        hdr[2] = red[0] + red[3] + red[6] + red[9];   // sumsq atoms
        candCnt[0] = 0u; candCnt[1] = 0u;
    }
}

// ---------------------------------------------------------------------------
// MFMA fm kernel — VERBATIM r11/r17 (233-238 us, MfmaUtil ~54%): counted-
// vmcnt 2-deep pipeline, raw barriers, setprio; epilogue reads TWO SCALARS.
// ---------------------------------------------------------------------------
#define XRW      2175      // reversed-window elements: [t0-2047 .. t0+127]
#define XRSTRIDE 2192      // elems per copy (4384 B: mult of 8, == 32 mod 128)
#define XRB      4384
#define NCPY     4
#define SA_BUF   16384     // bytes per A buffer (128 rows x 8 blk x 16B)

__device__ inline void gload_lds16(const unsigned short* g, unsigned char* lds) {
    __builtin_amdgcn_global_load_lds((const __attribute__((address_space(1))) void*)g,
                                     (__attribute__((address_space(3))) void*)lds,
                                     16, 0, 0);
}

__global__ __launch_bounds__(256, 3)
void fm_kernel(const float* __restrict__ x,
               const unsigned short* __restrict__ ab16,
               const float* __restrict__ hdr, unsigned* __restrict__ candCnt,
               Cand* __restrict__ cand, unsigned cap)
{
    __shared__ __align__(16) unsigned char  sA[2 * SA_BUF];
    __shared__ __align__(16) unsigned short sXR[NCPY * XRSTRIDE];

    const int bid = blockIdx.x;
    const int b   = bid >> 11;          // grid = 2 * 8 * 256
    const int rem = bid & 2047;
    const int a0  = (rem >> 8) * 128;
    const int t0  = (rem & 255) * 128;

    const int tid  = threadIdx.x;
    const int lane = tid & 63;
    const int wid  = tid >> 6;
    const int wm   = wid >> 1;          // 0..1 (m 64-block)
    const int wn   = wid & 1;           // 0..1 (n 64-block)
    const int g    = lane >> 4;         // k-group 0..3
    const int ln   = lane & 15;

    const int rot = (bid * 5) & 31;     // per-block K-chunk rotation

    const float* __restrict__ xb = x + b * NS;

    // ---- stage reversed x window as bf16, 4 shifted copies ----
    for (int ti = tid; ti < XRW; ti += 256) {
        int t = t0 - 2047 + ti;
        float f = (t >= 0) ? xb[t] : 0.f;
        unsigned short h = f2bf(f);
        int p0 = 2174 - ti;                       // xr[p] = x[t0+127-p]
        #pragma unroll
        for (int m = 0; m < NCPY; ++m) sXR[m * XRSTRIDE + p0 + m] = h;
    }

    // stage A chunk `ck` (64 k-elems) into buffer `bf`
    #define STAGE(bf, ck) do {                                                   \
        int kcs = (ck) * 64;                                                     \
        _Pragma("unroll")                                                        \
        for (int it = 0; it < 4; ++it) {                                         \
            int slot = (wid * 4 + it) * 64 + lane;                               \
            int row  = slot >> 3;                                                \
            int blk  = slot & 7;                                                 \
            const unsigned short* gsrc =                                         \
                ab16 + (size_t)(a0 + row) * AL + kcs + ((blk ^ (row & 7)) << 3); \
            gload_lds16(gsrc, sA + (bf) * SA_BUF + (size_t)(wid * 4 + it) * 1024); \
        }                                                                        \
    } while (0)

    f32x4 acc[4][4];
    #pragma unroll
    for (int i = 0; i < 4; ++i)
        #pragma unroll
        for (int j = 0; j < 4; ++j) acc[i][j] = (f32x4)0.0f;

    // lane-constant base: R(ni,S) = Rbase - 16*ni + 32*S
    const int Rbase = 127 - wn * 64 - ln + 8 * g;
    const unsigned char* xrb = (const unsigned char*)sXR;

    // lane-constant A-read offsets: row&7 == ln&7 (wm*64, mi*16 mults of 8)
    int rowoff[4];
    #pragma unroll
    for (int mi = 0; mi < 4; ++mi) rowoff[mi] = (wm * 64 + mi * 16 + ln) * 128;
    const int swz0 = ((0 * 4 + g) ^ (ln & 7)) << 4;   // s=0 swizzled blk byte-off
    const int swz1 = ((1 * 4 + g) ^ (ln & 7)) << 4;   // s=1

    // loadB(R): p = (R+3)&~3 (8B-aligned slot), copy m = p-R, two b64 reads
    #define LOADB(Rv, dst) do {                                                 \
        int p_ = ((Rv) + 3) & ~3;                                               \
        const unsigned char* a_ =                                               \
            xrb + (unsigned)(p_ - (Rv)) * XRB + (unsigned)p_ * 2u;              \
        short4v lo_ = *(const short4v*)a_;                                      \
        short4v hi_ = *(const short4v*)(a_ + 8);                                \
        dst = __builtin_shufflevector(lo_, hi_, 0, 1, 2, 3, 4, 5, 6, 7);        \
    } while (0)

    short8 b0, b1, b2, b3;

    #define LOADB4(Sv) do {                        \
        LOADB(Rbase      + 32 * (Sv), b0);         \
        LOADB(Rbase - 16 + 32 * (Sv), b1);         \
        LOADB(Rbase - 32 + 32 * (Sv), b2);         \
        LOADB(Rbase - 48 + 32 * (Sv), b3);         \
    } while (0)

    // frag(ni,S+1) = frag(ni-2,S): shift chain + 2 fresh
    #define ROLLB(Sv) do {                         \
        b3 = b1; b2 = b0;                          \
        LOADB(Rbase      + 32 * (Sv), b0);         \
        LOADB(Rbase - 16 + 32 * (Sv), b1);         \
    } while (0)

    #define MFMAS(mi) do {                                                                  \
        acc[mi][0] = __builtin_amdgcn_mfma_f32_16x16x32_bf16(af[mi], b0, acc[mi][0],0,0,0); \
        acc[mi][1] = __builtin_amdgcn_mfma_f32_16x16x32_bf16(af[mi], b1, acc[mi][1],0,0,0); \
        acc[mi][2] = __builtin_amdgcn_mfma_f32_16x16x32_bf16(af[mi], b2, acc[mi][2],0,0,0); \
        acc[mi][3] = __builtin_amdgcn_mfma_f32_16x16x32_bf16(af[mi], b3, acc[mi][3],0,0,0); \
    } while (0)

    __syncthreads();          // XR ds_writes drained + published

    LOADB4(rot * 2);          // B frags for first chunk

    STAGE(0, rot);                       // chunk c=0 (2-deep prologue)
    STAGE(1, (rot + 1) & 31);            // chunk c=1; 8 loads now in flight

    for (int c = 0; c < 32; ++c) {
        const int chunk  = (c + rot) & 31;
        const int nchunk = (c + 1 + rot) & 31;
        const int cur    = c & 1;

        // wait for chunk c's 4 loads (issued 2 iterations ago); newer 4 stay in flight
        asm volatile("s_waitcnt vmcnt(4)" ::: "memory");
        __builtin_amdgcn_sched_barrier(0);
        __builtin_amdgcn_s_barrier();
        __builtin_amdgcn_sched_barrier(0);

        #pragma unroll
        for (int s = 0; s < 2; ++s) {
            short8 af[4];
            const int soff = cur * SA_BUF + (s ? swz1 : swz0);
            #pragma unroll
            for (int mi = 0; mi < 4; ++mi)
                af[mi] = *(const short8*)(sA + soff + rowoff[mi]);

            __builtin_amdgcn_s_setprio(1);
            MFMAS(0); MFMAS(1); MFMAS(2); MFMAS(3);
            __builtin_amdgcn_s_setprio(0);

            if (s == 0) {
                ROLLB(chunk * 2 + 1);
            } else {
                if (nchunk == 0) { LOADB4(0); }     // wrap (or dead tail)
                else             { ROLLB(nchunk * 2); }
            }
        }

        // all waves done reading buf[cur]
        __builtin_amdgcn_sched_barrier(0);
        __builtin_amdgcn_s_barrier();
        __builtin_amdgcn_sched_barrier(0);

        // re-stage freed buffer with chunk c+2 (dead for c>=30 but load-bearing
        // for the vmcnt(4) counting discipline)
        STAGE(cur, (c + 2 + rot) & 31);
    }
    #undef LOADB
    #undef LOADB4
    #undef ROLLB
    #undef MFMAS
    #undef STAGE

    // ---- threshold + candidate append (two scalar hdr reads — r11 shape) ----
    const float sig = sqrtf((hdr[2] * (1.0f / (float)NA)) * (hdr[b] * (1.0f / (float)NS)));
    const float T0  = 3.70f * sig;   // cutoff ~4.01 sigma; bf16 noise ~0.002 sigma

    #pragma unroll
    for (int mi = 0; mi < 4; ++mi) {
        #pragma unroll
        for (int ni = 0; ni < 4; ++ni) {
            #pragma unroll
            for (int r = 0; r < 4; ++r) {
                float v = acc[mi][ni][r];
                if (v > T0) {
                    unsigned a = (unsigned)(a0 + wm * 64 + mi * 16 + g * 4 + r);
                    unsigned t = (unsigned)(t0 + wn * 64 + ni * 16 + ln);
                    unsigned idx = (a << 15) | t;
                    unsigned pos = atomicAdd(&candCnt[b], 1u);
                    if (pos < cap) {
                        Cand cc; cc.v = v; cc.idx = idx;
                        cand[(size_t)b * cap + pos] = cc;
                    }
                }
            }
        }
    }
}

// ---------------------------------------------------------------------------
// Merged refine+select (one node): 512 blocks run the band-limited fp64
// refine (v > 3.85*sig, one wave per candidate); the LAST block to finish
// (done-counter mod 512 + threadfence acquire — pattern validated in prep)
// runs the exact top-KKEEP selection for both batches (binary search on
// threshold; ties by ascending flat index = jax.lax.top_k semantics).
// ---------------------------------------------------------------------------
#define SELCAP  12288
#define RS_GRID 512

__global__ __launch_bounds__(256)
void refine_select(const float* __restrict__ x, const float* __restrict__ atoms,
                   const float* __restrict__ hdr,
                   const unsigned* __restrict__ candCnt, Cand* __restrict__ cand,
                   Cand* __restrict__ sel, unsigned* __restrict__ done, unsigned cap) {
    __shared__ float    s_vals[SELCAP];
    __shared__ float    s_red[4];
    __shared__ int      s_cnt;
    __shared__ int      s_nA;
    __shared__ int      s_nT;
    __shared__ int      s_exact;
    __shared__ float    s_tau;
    __shared__ Cand     s_A[KKEEP];
    __shared__ unsigned s_T[256];
    __shared__ int      isLast;

    const int tid  = threadIdx.x;
    const int lane = tid & 63;

    const float TB0 = 3.85f * sqrtf((hdr[2] * (1.0f / (float)NA)) * (hdr[0] * (1.0f / (float)NS)));
    const float TB1 = 3.85f * sqrtf((hdr[2] * (1.0f / (float)NA)) * (hdr[1] * (1.0f / (float)NS)));

    const int n0 = (int)min(candCnt[0], cap);
    const int n1 = (int)min(candCnt[1], cap);
    const int total = n0 + n1;

    // ---- refine phase (grid-strided over candidates, one wave each) ----
    {
        const int wv = (int)((blockIdx.x * 256 + tid) >> 6);
        const int nw = RS_GRID * 4;
        for (int c = wv; c < total; c += nw) {
            const int b = (c < n0) ? 0 : 1;
            const size_t ci = (c < n0) ? (size_t)c : ((size_t)cap + (size_t)(c - n0));
            const Cand cc = cand[ci];
            if (cc.v <= ((b == 0) ? TB0 : TB1)) continue;   // wave-uniform
            const unsigned idx = cc.idx;
            const int a = (int)(idx >> 15);
            const int t = (int)(idx & (NS - 1));
            const float* __restrict__ ar = atoms + (size_t)a * AL;
            const float* __restrict__ xr = x + b * NS;
            double s = 0.0;
            for (int k = lane; k < AL; k += 64) {
                int xi = t - k;
                if (xi >= 0) s += (double)ar[k] * (double)xr[xi];
            }
            #pragma unroll
            for (int o = 32; o >= 1; o >>= 1) s += __shfl_down(s, o);
            if (lane == 0) cand[ci].v = (float)s;
        }
    }

    // ---- done-counter: last block proceeds to selection ----
    if (tid == 0) {
        __threadfence();                              // release cand writes
        unsigned old = atomicAdd(done, 1u);
        isLast = (((old + 1u) & (RS_GRID - 1u)) == 0u) ? 1 : 0;
    }
    __syncthreads();
    if (!isLast) return;
    __threadfence();                                  // acquire cand

    // ---- selection, batches sequentially (256 threads) ----
    for (int b = 0; b < 2; ++b) {
        const Cand* __restrict__ cb = cand + (size_t)b * cap;
        const int n = (b == 0) ? n0 : n1;
        __syncthreads();                              // LDS reuse guard

        if (n <= KKEEP) {                             // statistically unreachable
            for (int i = tid; i < KKEEP; i += 256) {
                Cand z; z.v = 0.f; z.idx = 0u;
                sel[b * KKEEP + i] = (i < n) ? cb[i] : z;
            }
            continue;
        }

        const bool useLds = (n <= SELCAP);
        if (useLds)
            for (int i = tid; i < n; i += 256) s_vals[i] = cb[i].v;
        if (tid == 0) s_exact = 0;
        __syncthreads();

        float m = 0.f;
        if (useLds) for (int i = tid; i < n; i += 256) m = fmaxf(m, s_vals[i]);
        else        for (int i = tid; i < n; i += 256) m = fmaxf(m, cb[i].v);
        #pragma unroll
        for (int o = 32; o >= 1; o >>= 1) m = fmaxf(m, __shfl_down(m, o));
        if ((tid & 63) == 0) s_red[tid >> 6] = m;
        __syncthreads();
        float hi = fmaxf(fmaxf(s_red[0], s_red[1]), fmaxf(s_red[2], s_red[3]));
        float lo = 0.f;
        for (int iter = 0; iter < 64; ++iter) {
            float mid = 0.5f * (lo + hi);
            if (!(mid > lo && mid < hi)) break;
            if (tid == 0) s_cnt = 0;
            __syncthreads();
            int c = 0;
            if (useLds) for (int i = tid; i < n; i += 256) c += (s_vals[i] > mid) ? 1 : 0;
            else        for (int i = tid; i < n; i += 256) c += (cb[i].v  > mid) ? 1 : 0;
            #pragma unroll
            for (int o = 32; o >= 1; o >>= 1) c += __shfl_down(c, o);
            if ((tid & 63) == 0) atomicAdd(&s_cnt, c);
            __syncthreads();
            int cm = s_cnt;
            __syncthreads();
            if (cm == KKEEP) { if (tid == 0) { s_tau = mid; s_exact = 1; } break; }
            if (cm > KKEEP) lo = mid; else hi = mid;
        }
        __syncthreads();

        const int   exact = s_exact;
        const float tau   = exact ? s_tau : hi;

        for (int i = tid; i < KKEEP; i += 256) { s_A[i].v = 0.f; s_A[i].idx = 0u; }
        if (tid == 0) { s_nA = 0; s_nT = 0; }
        __syncthreads();

        for (int i = tid; i < n; i += 256) {
            float v = cb[i].v;
            if (v > tau) {
                int p = atomicAdd(&s_nA, 1);
                if (p < KKEEP) s_A[p] = cb[i];
            } else if (!exact && v == tau) {
                int p = atomicAdd(&s_nT, 1);
                if (p < 256) s_T[p] = cb[i].idx;
            }
        }
        __syncthreads();
        if (tid == 0) {
            int nA = s_nA; if (nA > KKEEP) nA = KKEEP;
            int need = KKEEP - nA;
            int nT = s_nT; if (nT > 256) nT = 256;
            for (int r = 0; r < need && r < nT; ++r) {   // ties: ascending index
                unsigned best = 0xffffffffu; int bj = -1;
                for (int j = 0; j < nT; ++j) if (s_T[j] < best) { best = s_T[j]; bj = j; }
                Cand c; c.v = tau; c.idx = best;
                s_A[nA + r] = c;
                if (bj >= 0) s_T[bj] = 0xffffffffu;
            }
        }
        __syncthreads();
        for (int i = tid; i < KKEEP; i += 256) sel[b * KKEEP + i] = s_A[i];
    }
}

// ---------------------------------------------------------------------------
// recon[b,t] = sum_e val_e * atoms[a_e, t - t0_e]  (gather, per-segment filter)
// ---------------------------------------------------------------------------
__global__ void recon_kernel(const float* __restrict__ atoms, const Cand* __restrict__ sel,
                             float* __restrict__ out) {
    __shared__ float s_cv[KKEEP];
    __shared__ int   s_ca[KKEEP];
    __shared__ int   s_ct[KKEEP];
    __shared__ int   s_n;
    const int b    = blockIdx.x >> 7;                    // 128 blocks per batch
    const int tseg = (blockIdx.x & 127) << 8;
    const int t    = tseg + threadIdx.x;
    if (threadIdx.x == 0) s_n = 0;
    __syncthreads();
    for (int i = threadIdx.x; i < KKEEP; i += blockDim.x) {
        Cand c = sel[b * KKEEP + i];
        int t0e = (int)(c.idx & (NS - 1));
        if (c.v != 0.f && t0e <= tseg + 255 && t0e + (AL - 1) >= tseg) {
            int p = atomicAdd(&s_n, 1);
            s_cv[p] = c.v;
            s_ca[p] = (int)(c.idx >> 15);
            s_ct[p] = t0e;
        }
    }
    __syncthreads();
    const int n = s_n;
    float acc = 0.f;
    for (int e = 0; e < n; ++e) {
        int d = t - s_ct[e];
        if ((unsigned)d < (unsigned)AL)
            acc += s_cv[e] * atoms[(size_t)s_ca[e] * AL + d];
    }
    out[b * NS + t] = acc;
}

extern "C" void kernel_launch(void* const* d_in, const int* in_sizes, int n_in,
                              void* d_out, int out_size, void* d_ws, size_t ws_size,
                              hipStream_t stream) {
    const float* x     = (const float*)d_in[0];   // (2,1,32768)
    const float* atoms = (const float*)d_in[1];   // (1,1024,2048)
    float* out = (float*)d_out;                   // (2,1,32768)

    float*          hdr     = (float*)d_ws;
    unsigned*       candCnt = (unsigned*)((char*)d_ws + 16);
    unsigned*       done    = (unsigned*)((char*)d_ws + 32);   // done[0]=prep, done[1]=refine_select
    float*          psum    = (float*)((char*)d_ws + 64);
    Cand*           sel     = (Cand*)((char*)d_ws + 32768);
    unsigned short* ab16    = (unsigned short*)((char*)d_ws + 65536);
    const size_t    candOff = 65536 + (size_t)NA * AL * 2;   // 4,259,840
    Cand*           cand    = (Cand*)((char*)d_ws + candOff);

    unsigned cap = CAPC;
    if (ws_size > candOff + 2 * sizeof(Cand) * 1024) {
        size_t fit = (ws_size - candOff) / (2 * sizeof(Cand));
        if (fit < cap) cap = (unsigned)fit;
    } else {
        cap = 1024;
    }

    prep_kernel  <<<2048, 256, 0, stream>>>(x, atoms, psum, hdr, candCnt, done, ab16);
    fm_kernel    <<<2 * (NA / 128) * (NS / 128), 256, 0, stream>>>(x, ab16, hdr, candCnt, cand, cap);
    refine_select<<<RS_GRID, 256, 0, stream>>>(x, atoms, hdr, candCnt, cand, sel, done + 1, cap);
    recon_kernel <<<256, 256, 0, stream>>>(atoms, sel, out);
}

// Round 19
// 370.692 us; speedup vs baseline: 1.0479x; 1.0479x over previous
//
#include <hip/hip_runtime.h>
#include <hip/hip_bf16.h>

#define NS    32768    // samples
#define NA    1024     // atoms
#define AL    2048     // atom length
#define KKEEP 1024     // top-k
#define CAPC  (512*1024)

struct Cand { float v; unsigned idx; };

typedef short  short8  __attribute__((ext_vector_type(8)));
typedef short  short4v __attribute__((ext_vector_type(4)));
typedef float  f32x4   __attribute__((ext_vector_type(4)));

// ---------------------------------------------------------------------------
// ws layout (bytes):
//   0       : float hdr[3]   { sumsq x[b=0], sumsq x[b=1], sumsq atoms }
//             (written by prep's LAST block each call — no memset needed)
//   16      : unsigned candCnt[2]   (zeroed by prep's last block)
//   32      : unsigned done         (monotone counter; mod-2048 logic ->
//                                    poison-proof, replay-deterministic)
//   64      : float psum[2048][3]   (24 KB, per-prep-block partials)
//   32768   : Cand sel[2][KKEEP]
//   65536   : unsigned short ab16[1024*2048]   (4 MB, bf16 atoms)
//   4259840 : Cand cand[2][cap]
//
// FINAL configuration (r17, session best = 371 us):
// 5 nodes (prep, fm, refine, select, recon).
//   - fm reads ONLY two scalars from hdr (r12-r16: any in-fm reduce, even
//     768 B, costs 80-150 us).
//   - fm never touches af32 (r12/r13: L2 pollution of the ab16 working set,
//     FETCH 28->48 MB, MfmaUtil 52->31%).
//   - refine/select/recon stay separate nodes (r18: done-counter merge
//     serializes the selection at 1-block occupancy, -17 us).
// fm = 235 us vs 180 us register-resident instruction floor (r10 shadow);
// 7 schedule variants (r5-r10) failed to close that gap.  Tail ~136 us is
// ~45 us work + ~90 us inter-node overhead (irreducible by merging).
//
// Numerics contract:
//   fm (bf16 MFMA) error: std ~4.2e-4 abs (~0.002 sigma_fm)
//   candidate filter T0 = 3.70*sig; true top-1024 cutoff ~ 4.01*sig
//   fp64 refine band TB = 3.85*sig: every candidate at/above the cutoff is
//   refined exactly; unrefined candidates can never be selected.
// ---------------------------------------------------------------------------

__device__ inline unsigned short f2bf(float f) {
    union { float f; unsigned u; } v; v.f = f;
    unsigned r = v.u + 0x7fffu + ((v.u >> 16) & 1u);   // round-to-nearest-even
    return (unsigned short)(r >> 16);
}

// ---------------------------------------------------------------------------
// prep: atoms f32->bf16 convert + per-block partials; the LAST block to
// finish (done-counter, mod-2048) reduces psum -> hdr in a FIXED order
// (bit-deterministic regardless of which block finishes) + zeroes candCnt.
// ---------------------------------------------------------------------------
__global__ void prep_kernel(const float* __restrict__ x, const float* __restrict__ atoms,
                            float* __restrict__ psum, float* __restrict__ hdr,
                            unsigned* __restrict__ candCnt, unsigned* __restrict__ done,
                            unsigned short* __restrict__ ab16) {
    __shared__ float red[12];
    __shared__ int   isLast;
    const int bid = blockIdx.x;                       // grid = 2048
    const int tid = threadIdx.x;
    const int i   = bid * 256 + tid;
    float4 f = *(const float4*)(atoms + (size_t)i * 4);
    ushort4 o;
    o.x = f2bf(f.x); o.y = f2bf(f.y); o.z = f2bf(f.z); o.w = f2bf(f.w);
    *(ushort4*)(ab16 + (size_t)i * 4) = o;
    float sa  = f.x*f.x + f.y*f.y + f.z*f.z + f.w*f.w;
    float sx0 = 0.f, sx1 = 0.f;
    if (i < 16384) {
        float4 xv = *(const float4*)(x + (size_t)i * 4);
        float s = xv.x*xv.x + xv.y*xv.y + xv.z*xv.z + xv.w*xv.w;
        if (i < 8192) sx0 = s; else sx1 = s;
    }
    #pragma unroll
    for (int off = 32; off >= 1; off >>= 1) {
        sa  += __shfl_down(sa , off);
        sx0 += __shfl_down(sx0, off);
        sx1 += __shfl_down(sx1, off);
    }
    if ((tid & 63) == 0) {
        red[(tid >> 6) * 3 + 0] = sa;
        red[(tid >> 6) * 3 + 1] = sx0;
        red[(tid >> 6) * 3 + 2] = sx1;
    }
    __syncthreads();
    if (tid == 0) {
        psum[bid * 3 + 0] = red[0] + red[3] + red[6] + red[9];
        psum[bid * 3 + 1] = red[1] + red[4] + red[7] + red[10];
        psum[bid * 3 + 2] = red[2] + red[5] + red[8] + red[11];
        __threadfence();                              // release psum
        unsigned old = atomicAdd(done, 1u);
        isLast = (((old + 1u) & 2047u) == 0u) ? 1 : 0;
    }
    __syncthreads();
    if (!isLast) return;

    // last block: reduce all partials -> hdr (fixed order => deterministic)
    __threadfence();                                  // acquire psum
    float pa = 0.f, p0s = 0.f, p1s = 0.f;
    for (int j = tid; j < 2048; j += 256) {
        pa  += psum[3 * j + 0];
        p0s += psum[3 * j + 1];
        p1s += psum[3 * j + 2];
    }
    #pragma unroll
    for (int off = 32; off >= 1; off >>= 1) {
        pa  += __shfl_down(pa , off);
        p0s += __shfl_down(p0s, off);
        p1s += __shfl_down(p1s, off);
    }
    __syncthreads();                                  // red[] reuse guard
    if ((tid & 63) == 0) {
        red[(tid >> 6) * 3 + 0] = pa;
        red[(tid >> 6) * 3 + 1] = p0s;
        red[(tid >> 6) * 3 + 2] = p1s;
    }
    __syncthreads();
    if (tid == 0) {
        hdr[0] = red[1] + red[4] + red[7] + red[10];  // sumsq x[b=0]
        hdr[1] = red[2] + red[5] + red[8] + red[11];  // sumsq x[b=1]
        hdr[2] = red[0] + red[3] + red[6] + red[9];   // sumsq atoms
        candCnt[0] = 0u; candCnt[1] = 0u;
    }
}

// ---------------------------------------------------------------------------
// MFMA fm kernel — r11/r17 proven form (233-238 us, MfmaUtil ~54%):
// counted-vmcnt 2-deep pipeline, raw barriers, setprio; epilogue reads TWO
// SCALARS from hdr (no reduce, no extra barrier).
//
// B operand (x Toeplitz) from REVERSED bf16 x-window in LDS:
// frag elem j = xr[R+j], R(ni,S) = Rbase - 16*ni + 32*S,
// Rbase = 127 - wn*64 - ln + 8*g, xr[p] = x[t0+127-p].
// Rolling identity: frag(ni,S+1) = frag(ni-2,S) -> 2 fresh loads per k-step.
// 4 shifted copies (p=(R+3)&~3, m=p-R in 0..3, stride 4384 B == 32 mod 128):
// each B-frag = two 8B-aligned ds_read_b64.
// A tile staged via global_load_lds(16B), XOR swizzle folded into the
// per-lane GLOBAL source address (LDS dest linear); read back with
// blk' = blk ^ (row&7) -> conflict-free ds_read_b128.
// K-chunk order rotated per block ((c+rot)&31) to de-convoy L2.
// NOTE: the "dead" STAGEs at c>=30 are load-bearing for vmcnt(4) counting.
// ---------------------------------------------------------------------------
#define XRW      2175      // reversed-window elements: [t0-2047 .. t0+127]
#define XRSTRIDE 2192      // elems per copy (4384 B: mult of 8, == 32 mod 128)
#define XRB      4384
#define NCPY     4
#define SA_BUF   16384     // bytes per A buffer (128 rows x 8 blk x 16B)

__device__ inline void gload_lds16(const unsigned short* g, unsigned char* lds) {
    __builtin_amdgcn_global_load_lds((const __attribute__((address_space(1))) void*)g,
                                     (__attribute__((address_space(3))) void*)lds,
                                     16, 0, 0);
}

__global__ __launch_bounds__(256, 3)
void fm_kernel(const float* __restrict__ x,
               const unsigned short* __restrict__ ab16,
               const float* __restrict__ hdr, unsigned* __restrict__ candCnt,
               Cand* __restrict__ cand, unsigned cap)
{
    __shared__ __align__(16) unsigned char  sA[2 * SA_BUF];
    __shared__ __align__(16) unsigned short sXR[NCPY * XRSTRIDE];

    const int bid = blockIdx.x;
    const int b   = bid >> 11;          // grid = 2 * 8 * 256
    const int rem = bid & 2047;
    const int a0  = (rem >> 8) * 128;
    const int t0  = (rem & 255) * 128;

    const int tid  = threadIdx.x;
    const int lane = tid & 63;
    const int wid  = tid >> 6;
    const int wm   = wid >> 1;          // 0..1 (m 64-block)
    const int wn   = wid & 1;           // 0..1 (n 64-block)
    const int g    = lane >> 4;         // k-group 0..3
    const int ln   = lane & 15;

    const int rot = (bid * 5) & 31;     // per-block K-chunk rotation

    const float* __restrict__ xb = x + b * NS;

    // ---- stage reversed x window as bf16, 4 shifted copies ----
    for (int ti = tid; ti < XRW; ti += 256) {
        int t = t0 - 2047 + ti;
        float f = (t >= 0) ? xb[t] : 0.f;
        unsigned short h = f2bf(f);
        int p0 = 2174 - ti;                       // xr[p] = x[t0+127-p]
        #pragma unroll
        for (int m = 0; m < NCPY; ++m) sXR[m * XRSTRIDE + p0 + m] = h;
    }

    // stage A chunk `ck` (64 k-elems) into buffer `bf`
    #define STAGE(bf, ck) do {                                                   \
        int kcs = (ck) * 64;                                                     \
        _Pragma("unroll")                                                        \
        for (int it = 0; it < 4; ++it) {                                         \
            int slot = (wid * 4 + it) * 64 + lane;                               \
            int row  = slot >> 3;                                                \
            int blk  = slot & 7;                                                 \
            const unsigned short* gsrc =                                         \
                ab16 + (size_t)(a0 + row) * AL + kcs + ((blk ^ (row & 7)) << 3); \
            gload_lds16(gsrc, sA + (bf) * SA_BUF + (size_t)(wid * 4 + it) * 1024); \
        }                                                                        \
    } while (0)

    f32x4 acc[4][4];
    #pragma unroll
    for (int i = 0; i < 4; ++i)
        #pragma unroll
        for (int j = 0; j < 4; ++j) acc[i][j] = (f32x4)0.0f;

    // lane-constant base: R(ni,S) = Rbase - 16*ni + 32*S
    const int Rbase = 127 - wn * 64 - ln + 8 * g;
    const unsigned char* xrb = (const unsigned char*)sXR;

    // lane-constant A-read offsets: row&7 == ln&7 (wm*64, mi*16 mults of 8)
    int rowoff[4];
    #pragma unroll
    for (int mi = 0; mi < 4; ++mi) rowoff[mi] = (wm * 64 + mi * 16 + ln) * 128;
    const int swz0 = ((0 * 4 + g) ^ (ln & 7)) << 4;   // s=0 swizzled blk byte-off
    const int swz1 = ((1 * 4 + g) ^ (ln & 7)) << 4;   // s=1

    // loadB(R): p = (R+3)&~3 (8B-aligned slot), copy m = p-R, two b64 reads
    #define LOADB(Rv, dst) do {                                                 \
        int p_ = ((Rv) + 3) & ~3;                                               \
        const unsigned char* a_ =                                               \
            xrb + (unsigned)(p_ - (Rv)) * XRB + (unsigned)p_ * 2u;              \
        short4v lo_ = *(const short4v*)a_;                                      \
        short4v hi_ = *(const short4v*)(a_ + 8);                                \
        dst = __builtin_shufflevector(lo_, hi_, 0, 1, 2, 3, 4, 5, 6, 7);        \
    } while (0)

    short8 b0, b1, b2, b3;

    #define LOADB4(Sv) do {                        \
        LOADB(Rbase      + 32 * (Sv), b0);         \
        LOADB(Rbase - 16 + 32 * (Sv), b1);         \
        LOADB(Rbase - 32 + 32 * (Sv), b2);         \
        LOADB(Rbase - 48 + 32 * (Sv), b3);         \
    } while (0)

    // frag(ni,S+1) = frag(ni-2,S): shift chain + 2 fresh
    #define ROLLB(Sv) do {                         \
        b3 = b1; b2 = b0;                          \
        LOADB(Rbase      + 32 * (Sv), b0);         \
        LOADB(Rbase - 16 + 32 * (Sv), b1);         \
    } while (0)

    #define MFMAS(mi) do {                                                                  \
        acc[mi][0] = __builtin_amdgcn_mfma_f32_16x16x32_bf16(af[mi], b0, acc[mi][0],0,0,0); \
        acc[mi][1] = __builtin_amdgcn_mfma_f32_16x16x32_bf16(af[mi], b1, acc[mi][1],0,0,0); \
        acc[mi][2] = __builtin_amdgcn_mfma_f32_16x16x32_bf16(af[mi], b2, acc[mi][2],0,0,0); \
        acc[mi][3] = __builtin_amdgcn_mfma_f32_16x16x32_bf16(af[mi], b3, acc[mi][3],0,0,0); \
    } while (0)

    __syncthreads();          // XR ds_writes drained + published

    LOADB4(rot * 2);          // B frags for first chunk

    STAGE(0, rot);                       // chunk c=0 (2-deep prologue)
    STAGE(1, (rot + 1) & 31);            // chunk c=1; 8 loads now in flight

    for (int c = 0; c < 32; ++c) {
        const int chunk  = (c + rot) & 31;
        const int nchunk = (c + 1 + rot) & 31;
        const int cur    = c & 1;

        // wait for chunk c's 4 loads (issued 2 iterations ago); newer 4 stay in flight
        asm volatile("s_waitcnt vmcnt(4)" ::: "memory");
        __builtin_amdgcn_sched_barrier(0);
        __builtin_amdgcn_s_barrier();
        __builtin_amdgcn_sched_barrier(0);

        #pragma unroll
        for (int s = 0; s < 2; ++s) {
            short8 af[4];
            const int soff = cur * SA_BUF + (s ? swz1 : swz0);
            #pragma unroll
            for (int mi = 0; mi < 4; ++mi)
                af[mi] = *(const short8*)(sA + soff + rowoff[mi]);

            __builtin_amdgcn_s_setprio(1);
            MFMAS(0); MFMAS(1); MFMAS(2); MFMAS(3);
            __builtin_amdgcn_s_setprio(0);

            if (s == 0) {
                ROLLB(chunk * 2 + 1);
            } else {
                if (nchunk == 0) { LOADB4(0); }     // wrap (or dead tail)
                else             { ROLLB(nchunk * 2); }
            }
        }

        // all waves done reading buf[cur]
        __builtin_amdgcn_sched_barrier(0);
        __builtin_amdgcn_s_barrier();
        __builtin_amdgcn_sched_barrier(0);

        // re-stage freed buffer with chunk c+2 (dead for c>=30 but load-bearing
        // for the vmcnt(4) counting discipline)
        STAGE(cur, (c + 2 + rot) & 31);
    }
    #undef LOADB
    #undef LOADB4
    #undef ROLLB
    #undef MFMAS
    #undef STAGE

    // ---- threshold + candidate append (two scalar hdr reads — r11 shape) ----
    const float sig = sqrtf((hdr[2] * (1.0f / (float)NA)) * (hdr[b] * (1.0f / (float)NS)));
    const float T0  = 3.70f * sig;   // cutoff ~4.01 sigma; bf16 noise ~0.002 sigma

    #pragma unroll
    for (int mi = 0; mi < 4; ++mi) {
        #pragma unroll
        for (int ni = 0; ni < 4; ++ni) {
            #pragma unroll
            for (int r = 0; r < 4; ++r) {
                float v = acc[mi][ni][r];
                if (v > T0) {
                    unsigned a = (unsigned)(a0 + wm * 64 + mi * 16 + g * 4 + r);
                    unsigned t = (unsigned)(t0 + wn * 64 + ni * 16 + ln);
                    unsigned idx = (a << 15) | t;
                    unsigned pos = atomicAdd(&candCnt[b], 1u);
                    if (pos < cap) {
                        Cand cc; cc.v = v; cc.idx = idx;
                        cand[(size_t)b * cap + pos] = cc;
                    }
                }
            }
        }
    }
}

// ---------------------------------------------------------------------------
// Band-limited exact fp64 re-evaluation (separate node, AFTER fm — r12/r13
// lesson: its af32 streaming must not pollute fm's L2 working set):
// candidates with v > 3.85*sig, one wave per candidate.  Thresholds from hdr.
// ---------------------------------------------------------------------------
__global__ void refine_band(const float* __restrict__ x, const float* __restrict__ atoms,
                            const float* __restrict__ hdr,
                            const unsigned* __restrict__ candCnt, Cand* __restrict__ cand,
                            unsigned cap) {
    const int lane = threadIdx.x & 63;
    const float TB0 = 3.85f * sqrtf((hdr[2] * (1.0f / (float)NA)) * (hdr[0] * (1.0f / (float)NS)));
    const float TB1 = 3.85f * sqrtf((hdr[2] * (1.0f / (float)NA)) * (hdr[1] * (1.0f / (float)NS)));

    const int wv = (int)((blockIdx.x * blockDim.x + threadIdx.x) >> 6);
    const int nw = (int)((gridDim.x * blockDim.x) >> 6);
    const int n0 = (int)min(candCnt[0], cap);
    const int n1 = (int)min(candCnt[1], cap);
    const int total = n0 + n1;
    for (int c = wv; c < total; c += nw) {
        const int b = (c < n0) ? 0 : 1;
        const size_t ci = (c < n0) ? (size_t)c : ((size_t)cap + (size_t)(c - n0));
        const Cand cc = cand[ci];
        if (cc.v <= ((b == 0) ? TB0 : TB1)) continue;   // wave-uniform branch
        const unsigned idx = cc.idx;
        const int a = (int)(idx >> 15);
        const int t = (int)(idx & (NS - 1));
        const float* __restrict__ ar = atoms + (size_t)a * AL;
        const float* __restrict__ xr = x + b * NS;
        double s = 0.0;
        for (int k = lane; k < AL; k += 64) {
            int xi = t - k;
            if (xi >= 0) s += (double)ar[k] * (double)xr[xi];
        }
        #pragma unroll
        for (int o = 32; o >= 1; o >>= 1) s += __shfl_down(s, o);
        if (lane == 0) cand[ci].v = (float)s;
    }
}

// ---------------------------------------------------------------------------
// Exact top-KKEEP among candidates (binary search on threshold; ties by
// ascending flat index = jax.lax.top_k semantics). One block per batch.
// Candidate values cached in LDS for the search sweeps.
// ---------------------------------------------------------------------------
#define SELCAP 16384

__global__ void select_kernel(const unsigned* __restrict__ candCnt,
                              const Cand* __restrict__ cand, Cand* __restrict__ sel,
                              unsigned cap) {
    __shared__ float    s_vals[SELCAP];
    __shared__ float    s_red[16];
    __shared__ int      s_cnt;
    __shared__ int      s_nA;
    __shared__ int      s_nT;
    __shared__ int      s_exact;
    __shared__ float    s_tau;
    __shared__ Cand     s_A[KKEEP];
    __shared__ unsigned s_T[256];

    const int b = blockIdx.x;
    const Cand* __restrict__ cb = cand + (size_t)b * cap;
    const int n   = (int)min(candCnt[b], cap);
    const int tid = threadIdx.x;

    if (n <= KKEEP) {   // statistically unreachable; safe fallback
        for (int i = tid; i < KKEEP; i += blockDim.x) {
            Cand z; z.v = 0.f; z.idx = 0u;
            sel[b * KKEEP + i] = (i < n) ? cb[i] : z;
        }
        return;
    }

    const bool useLds = (n <= SELCAP);
    if (useLds)
        for (int i = tid; i < n; i += blockDim.x) s_vals[i] = cb[i].v;

    float m = 0.f;
    if (useLds) { __syncthreads();
        for (int i = tid; i < n; i += blockDim.x) m = fmaxf(m, s_vals[i]);
    } else {
        for (int i = tid; i < n; i += blockDim.x) m = fmaxf(m, cb[i].v);
    }
    #pragma unroll
    for (int o = 32; o >= 1; o >>= 1) m = fmaxf(m, __shfl_down(m, o));
    if ((tid & 63) == 0) s_red[tid >> 6] = m;
    if (tid == 0) s_exact = 0;
    __syncthreads();
    float hi;
    {
        float mm = 0.f;
        #pragma unroll
        for (int w = 0; w < 16; ++w) mm = fmaxf(mm, s_red[w]);
        hi = mm;
    }
    float lo = 0.f;
    for (int iter = 0; iter < 64; ++iter) {
        float mid = 0.5f * (lo + hi);
        if (!(mid > lo && mid < hi)) break;
        if (tid == 0) s_cnt = 0;
        __syncthreads();
        int c = 0;
        if (useLds) for (int i = tid; i < n; i += blockDim.x) c += (s_vals[i] > mid) ? 1 : 0;
        else        for (int i = tid; i < n; i += blockDim.x) c += (cb[i].v  > mid) ? 1 : 0;
        #pragma unroll
        for (int o = 32; o >= 1; o >>= 1) c += __shfl_down(c, o);
        if ((tid & 63) == 0) atomicAdd(&s_cnt, c);
        __syncthreads();
        int cm = s_cnt;
        __syncthreads();
        if (cm == KKEEP) { if (tid == 0) { s_tau = mid; s_exact = 1; } break; }
        if (cm > KKEEP) lo = mid; else hi = mid;
    }
    __syncthreads();

    const int   exact = s_exact;
    const float tau   = exact ? s_tau : hi;

    for (int i = tid; i < KKEEP; i += blockDim.x) { s_A[i].v = 0.f; s_A[i].idx = 0u; }
    if (tid == 0) { s_nA = 0; s_nT = 0; }
    __syncthreads();

    for (int i = tid; i < n; i += blockDim.x) {
        float v = cb[i].v;
        if (v > tau) {
            int p = atomicAdd(&s_nA, 1);
            if (p < KKEEP) s_A[p] = cb[i];
        } else if (!exact && v == tau) {
            int p = atomicAdd(&s_nT, 1);
            if (p < 256) s_T[p] = cb[i].idx;
        }
    }
    __syncthreads();
    if (tid == 0) {
        int nA = s_nA; if (nA > KKEEP) nA = KKEEP;
        int need = KKEEP - nA;
        int nT = s_nT; if (nT > 256) nT = 256;
        for (int r = 0; r < need && r < nT; ++r) {
            unsigned best = 0xffffffffu; int bj = -1;
            for (int j = 0; j < nT; ++j) if (s_T[j] < best) { best = s_T[j]; bj = j; }
            Cand c; c.v = tau; c.idx = best;
            s_A[nA + r] = c;
            if (bj >= 0) s_T[bj] = 0xffffffffu;
        }
    }
    __syncthreads();
    for (int i = tid; i < KKEEP; i += blockDim.x) sel[b * KKEEP + i] = s_A[i];
}

// ---------------------------------------------------------------------------
// recon[b,t] = sum_e val_e * atoms[a_e, t - t0_e]  (gather, per-segment filter)
// ---------------------------------------------------------------------------
__global__ void recon_kernel(const float* __restrict__ atoms, const Cand* __restrict__ sel,
                             float* __restrict__ out) {
    __shared__ float s_cv[KKEEP];
    __shared__ int   s_ca[KKEEP];
    __shared__ int   s_ct[KKEEP];
    __shared__ int   s_n;
    const int b    = blockIdx.x >> 7;                    // 128 blocks per batch
    const int tseg = (blockIdx.x & 127) << 8;
    const int t    = tseg + threadIdx.x;
    if (threadIdx.x == 0) s_n = 0;
    __syncthreads();
    for (int i = threadIdx.x; i < KKEEP; i += blockDim.x) {
        Cand c = sel[b * KKEEP + i];
        int t0e = (int)(c.idx & (NS - 1));
        if (c.v != 0.f && t0e <= tseg + 255 && t0e + (AL - 1) >= tseg) {
            int p = atomicAdd(&s_n, 1);
            s_cv[p] = c.v;
            s_ca[p] = (int)(c.idx >> 15);
            s_ct[p] = t0e;
        }
    }
    __syncthreads();
    const int n = s_n;
    float acc = 0.f;
    for (int e = 0; e < n; ++e) {
        int d = t - s_ct[e];
        if ((unsigned)d < (unsigned)AL)
            acc += s_cv[e] * atoms[(size_t)s_ca[e] * AL + d];
    }
    out[b * NS + t] = acc;
}

extern "C" void kernel_launch(void* const* d_in, const int* in_sizes, int n_in,
                              void* d_out, int out_size, void* d_ws, size_t ws_size,
                              hipStream_t stream) {
    const float* x     = (const float*)d_in[0];   // (2,1,32768)
    const float* atoms = (const float*)d_in[1];   // (1,1024,2048)
    float* out = (float*)d_out;                   // (2,1,32768)

    float*          hdr     = (float*)d_ws;
    unsigned*       candCnt = (unsigned*)((char*)d_ws + 16);
    unsigned*       done    = (unsigned*)((char*)d_ws + 32);
    float*          psum    = (float*)((char*)d_ws + 64);
    Cand*           sel     = (Cand*)((char*)d_ws + 32768);
    unsigned short* ab16    = (unsigned short*)((char*)d_ws + 65536);
    const size_t    candOff = 65536 + (size_t)NA * AL * 2;   // 4,259,840
    Cand*           cand    = (Cand*)((char*)d_ws + candOff);

    unsigned cap = CAPC;
    if (ws_size > candOff + 2 * sizeof(Cand) * 1024) {
        size_t fit = (ws_size - candOff) / (2 * sizeof(Cand));
        if (fit < cap) cap = (unsigned)fit;
    } else {
        cap = 1024;
    }

    prep_kernel  <<<2048, 256, 0, stream>>>(x, atoms, psum, hdr, candCnt, done, ab16);
    fm_kernel    <<<2 * (NA / 128) * (NS / 128), 256, 0, stream>>>(x, ab16, hdr, candCnt, cand, cap);
    refine_band  <<<512, 256, 0, stream>>>(x, atoms, hdr, candCnt, cand, cap);
    select_kernel<<<2, 1024, 0, stream>>>(candCnt, cand, sel, cap);
    recon_kernel <<<256, 256, 0, stream>>>(atoms, sel, out);
}